// Round 1
// baseline (457.913 us; speedup 1.0000x reference)
//
#include <hip/hip_runtime.h>

typedef __bf16 bf16x8 __attribute__((ext_vector_type(8)));
typedef float f32x4 __attribute__((ext_vector_type(4)));

static constexpr int TOKS = 43520;   // B * LQ
static constexpr int LQN  = 21760;

__device__ __forceinline__ unsigned short f2bf(float f) {
  union { float f; unsigned u; } v; v.f = f;
  return (unsigned short)((v.u + 0x7fffu + ((v.u >> 16) & 1u)) >> 16);
}
__device__ __forceinline__ float bf2f(unsigned short b) {
  union { unsigned u; float f; } v; v.u = ((unsigned)b) << 16; return v.f;
}

// async global->LDS, 16B per lane. LDS dest must be wave-uniform base (linear fill).
__device__ __forceinline__ void gload16(const unsigned short* g, unsigned short* l) {
  __builtin_amdgcn_global_load_lds((const __attribute__((address_space(1))) unsigned int*)g,
                                   (__attribute__((address_space(3))) unsigned int*)l,
                                   16, 0, 0);
}

// ---- fused prep + weight transpose + bias concat (one launch)
__global__ __launch_bounds__(256) void prewt_kernel(
    const float* __restrict__ src, const float* __restrict__ pos,
    unsigned short* __restrict__ srcb, unsigned short* __restrict__ qb,
    const float* __restrict__ W_val, const float* __restrict__ W_off,
    const float* __restrict__ W_attn, const float* __restrict__ W_out,
    const float* __restrict__ W1, const float* __restrict__ W2,
    const float* __restrict__ b_off, const float* __restrict__ b_attn,
    unsigned short* __restrict__ Wt_val, unsigned short* __restrict__ Wt_oa,
    unsigned short* __restrict__ Wt_out,
    unsigned short* __restrict__ Wt_1, unsigned short* __restrict__ Wt_2,
    float* __restrict__ b_oa) {
  const int bid = blockIdx.x;
  if (bid < 10880) {
    int i = bid * 256 + threadIdx.x;
    float4 s = ((const float4*)src)[i], p = ((const float4*)pos)[i];
    ((ushort4*)srcb)[i] = make_ushort4(f2bf(s.x), f2bf(s.y), f2bf(s.z), f2bf(s.w));
    ((ushort4*)qb)[i]   = make_ushort4(f2bf(s.x + p.x), f2bf(s.y + p.y),
                                       f2bf(s.z + p.z), f2bf(s.w + p.w));
    return;
  }
  int gid = (bid - 10880) * 256 + threadIdx.x;
  if (gid >= 754048) return;
  if (gid >= 753664) {
    int i = gid - 753664;
    b_oa[i] = (i < 256) ? b_off[i] : b_attn[i - 256];
    return;
  }
  const float* W; unsigned short* Wt; int idx, K, nsh;
  if (gid < 65536)       { W = W_val;  Wt = Wt_val;          idx = gid;          K = 256;  nsh = 8;  }
  else if (gid < 131072) { W = W_off;  Wt = Wt_oa;           idx = gid - 65536;  K = 256;  nsh = 8;  }
  else if (gid < 163840) { W = W_attn; Wt = Wt_oa + 65536;   idx = gid - 131072; K = 256;  nsh = 7;  }
  else if (gid < 229376) { W = W_out;  Wt = Wt_out;          idx = gid - 163840; K = 256;  nsh = 8;  }
  else if (gid < 491520) { W = W1;     Wt = Wt_1;            idx = gid - 229376; K = 256;  nsh = 10; }
  else                   { W = W2;     Wt = Wt_2;            idx = gid - 491520; K = 1024; nsh = 8;  }
  int k = idx >> nsh, n = idx & ((1 << nsh) - 1);
  Wt[n * K + k] = f2bf(W[idx]);
}

// ---- GEMM body: global_load_lds staging (16B/lane), linear LDS [128][32] shorts,
// both-sides XOR chunk swizzle (c ^= row&3) to spread ds_read_b128 banks.
// Double-buffered, ONE barrier per K-iter.
// OUTOP: 1=bf16, 2=relu->bf16, 3=+res->bf16
template <int K, int OUTOP>
__device__ __forceinline__ void gemm_body(unsigned short* __restrict__ As,
                                          unsigned short* __restrict__ Bs,
                                          const unsigned short* __restrict__ A,
                                          const unsigned short* __restrict__ Bt,
                                          const float* __restrict__ bias,
                                          const unsigned short* __restrict__ res,
                                          unsigned short* __restrict__ Cp,
                                          int N, int bm, int bn) {
  const int t = threadIdx.x;
  const int wave = t >> 6, lane = t & 63;
  const int wm = (wave & 1) << 6, wn = (wave >> 1) << 6;
  const int lr = lane & 15, lq = lane >> 4;
  const int cA = (lq ^ (lr & 3)) * 8;            // swizzled read chunk (shorts)
  // staging: thread t fills LDS bytes [t*16, t*16+16) of a 4KB half-tile.
  // row = t>>2 (stride 64B), chunk = t&3; source column chunk is inverse-swizzled.
  const int srow = t >> 2;
  const int scol = ((t & 3) ^ (srow & 3)) * 8;   // shorts
  const unsigned short* gsA = A  + (size_t)(bm * 128 + srow) * K + scol;
  const unsigned short* gsB = Bt + (size_t)(bn * 128 + srow) * K + scol;
  const size_t gstep = (size_t)64 * K;
  f32x4 acc[4][4] = {};

  // prologue: stage k0=0 into buffer 0
  {
    unsigned short* Ad = As + wave * 512;
    unsigned short* Bd = Bs + wave * 512;
    gload16(gsA,         Ad);
    gload16(gsA + gstep, Ad + 2048);
    gload16(gsB,         Bd);
    gload16(gsB + gstep, Bd + 2048);
  }
  __syncthreads();
  int p = 0;
#pragma unroll 2
  for (int k0 = 0; k0 < K; k0 += 32) {
    if (k0 + 32 < K) {                 // stage next tile; flies during this iter's MFMA
      unsigned short* Ad = As + (p ^ 1) * 4096 + wave * 512;
      unsigned short* Bd = Bs + (p ^ 1) * 4096 + wave * 512;
      gload16(gsA + k0 + 32,         Ad);
      gload16(gsA + gstep + k0 + 32, Ad + 2048);
      gload16(gsB + k0 + 32,         Bd);
      gload16(gsB + gstep + k0 + 32, Bd + 2048);
    }
    const unsigned short* Ab = As + p * 4096;
    const unsigned short* Bb = Bs + p * 4096;
    bf16x8 af[4], bfr[4];
#pragma unroll
    for (int i = 0; i < 4; i++) af[i]  = *(const bf16x8*)&Ab[(wm + i * 16 + lr) * 32 + cA];
#pragma unroll
    for (int j = 0; j < 4; j++) bfr[j] = *(const bf16x8*)&Bb[(wn + j * 16 + lr) * 32 + cA];
#pragma unroll
    for (int i = 0; i < 4; i++)
#pragma unroll
      for (int j = 0; j < 4; j++)
        acc[i][j] = __builtin_amdgcn_mfma_f32_16x16x32_bf16(af[i], bfr[j], acc[i][j], 0, 0, 0);
    __syncthreads();                   // drains staged loads + read-done for dbuf swap
    p ^= 1;
  }
  // C/D mapping (m89/m91): col = lane&15, row = (lane>>4)*4 + reg
  const int rb = bm * 128 + wm + lq * 4;
  const int cbase = bn * 128 + wn + lr;
#pragma unroll
  for (int j = 0; j < 4; j++) {
    const int col = cbase + j * 16;
    const float bv = bias[col];
#pragma unroll
    for (int i = 0; i < 4; i++) {
#pragma unroll
      for (int r = 0; r < 4; r++) {
        float v = acc[i][j][r] + bv;
        size_t o = (size_t)(rb + i * 16 + r) * N + col;
        if (OUTOP == 1) Cp[o] = f2bf(v);
        else if (OUTOP == 2) Cp[o] = f2bf(fmaxf(v, 0.f));
        else Cp[o] = f2bf(v + bf2f(res[o]));
      }
    }
  }
}

__global__ __launch_bounds__(256) void proj_kernel(
    const unsigned short* __restrict__ srcb, const unsigned short* __restrict__ qb,
    const unsigned short* __restrict__ Wt_val, const unsigned short* __restrict__ Wt_oa,
    const float* __restrict__ b_val, const float* __restrict__ b_oa,
    unsigned short* __restrict__ valb, unsigned short* __restrict__ oab) {
  __shared__ unsigned short As[2 * 4096];
  __shared__ unsigned short Bs[2 * 4096];
  const int bn = blockIdx.y;
  if (bn < 2)
    gemm_body<256, 1>(As, Bs, srcb, Wt_val, b_val, nullptr, valb, 256, blockIdx.x, bn);
  else
    gemm_body<256, 1>(As, Bs, qb, Wt_oa, b_oa, nullptr, oab, 384, blockIdx.x, bn - 2);
}

__global__ __launch_bounds__(256) void gemm_out_kernel(
    const unsigned short* __restrict__ A, const unsigned short* __restrict__ Bt,
    const float* __restrict__ bias, const unsigned short* __restrict__ res,
    unsigned short* __restrict__ C) {
  __shared__ unsigned short As[2 * 4096];
  __shared__ unsigned short Bs[2 * 4096];
  gemm_body<256, 3>(As, Bs, A, Bt, bias, res, C, 256, blockIdx.x, blockIdx.y);
}

__global__ __launch_bounds__(256) void gemm_ffn1_kernel(
    const unsigned short* __restrict__ A, const unsigned short* __restrict__ Bt,
    const float* __restrict__ bias, unsigned short* __restrict__ C) {
  __shared__ unsigned short As[2 * 4096];
  __shared__ unsigned short Bs[2 * 4096];
  gemm_body<256, 2>(As, Bs, A, Bt, bias, nullptr, C, 1024, blockIdx.x, blockIdx.y);
}

__global__ __launch_bounds__(256) void gemm_ffn2_kernel(
    const unsigned short* __restrict__ A, const unsigned short* __restrict__ Bt,
    const float* __restrict__ bias, const unsigned short* __restrict__ res,
    unsigned short* __restrict__ C) {
  __shared__ unsigned short As[2 * 4096];
  __shared__ unsigned short Bs[2 * 4096];
  gemm_body<1024, 3>(As, Bs, A, Bt, bias, res, C, 256, blockIdx.x, blockIdx.y);
}

// ---- bf16x8 (uint4) fused unpack+FMA into fp32 acc
__device__ __forceinline__ void fma8(uint4 v, float w, float* a) {
  const unsigned uu[4] = {v.x, v.y, v.z, v.w};
#pragma unroll
  for (int i = 0; i < 4; i++) {
    union { unsigned u; float f; } lo, hi;
    lo.u = uu[i] << 16;
    hi.u = uu[i] & 0xffff0000u;
    a[2 * i]     += w * lo.f;
    a[2 * i + 1] += w * hi.f;
  }
}

// ---- deformable attention, two-phase.
// sI packed int2: corners are base, base+dx, base+dy, base+dx+dy with
// dx in {0,512}, dy in {0, S*512}; pack = dy | (dx>>9). LDS 26112B -> 6 blocks/CU.
__global__ __launch_bounds__(256) void deform_kernel(const unsigned short* __restrict__ valb,
                                                     const unsigned short* __restrict__ oab,
                                                     const float* __restrict__ refp,
                                                     unsigned short* __restrict__ outb) {
  __shared__ float4 sW[8][8][17];   // 4 corner weights (x attn)
  __shared__ int2   sI[8][8][17];   // base byte offset + packed (dy|dx>>9)
  const int t = threadIdx.x;
  const int bid = blockIdx.x;                     // 5440 blocks
  const int nb = (bid & 7) * 680 + (bid >> 3);    // XCD-contiguous slices
  const int tok0 = nb * 8;

  // ---- phase 1: thread = (g, h, l); softmax redundant x4, each builds 4 entries
  {
    const int g = t >> 5, h = (t >> 2) & 7, l = t & 3;
    const int tok = tok0 + g;
    const unsigned short* lg = oab + (size_t)tok * 384 + 256 + h * 16;
    uint4 lv0 = ((const uint4*)lg)[0];
    uint4 lv1 = ((const uint4*)lg)[1];
    const unsigned lw[8] = {lv0.x, lv0.y, lv0.z, lv0.w, lv1.x, lv1.y, lv1.z, lv1.w};
    float w[16];
#pragma unroll
    for (int i = 0; i < 8; i++) {
      union { unsigned u; float f; } lo, hi;
      lo.u = lw[i] << 16; hi.u = lw[i] & 0xffff0000u;
      w[2 * i] = lo.f; w[2 * i + 1] = hi.f;
    }
    float mx = -1e30f;
#pragma unroll
    for (int i = 0; i < 16; i++) mx = fmaxf(mx, w[i]);
    float s = 0.f;
#pragma unroll
    for (int i = 0; i < 16; i++) { w[i] = __expf(w[i] - mx); s += w[i]; }
    const float inv = 1.f / s;
    // this level's 8 offset values = one 16B load
    uint4 ov = *(const uint4*)(oab + (size_t)tok * 384 + h * 32 + l * 8);
    const unsigned owv[4] = {ov.x, ov.y, ov.z, ov.w};
    float off[8];
#pragma unroll
    for (int i = 0; i < 4; i++) {
      union { unsigned u; float f; } lo, hi;
      lo.u = owv[i] << 16; hi.u = owv[i] & 0xffff0000u;
      off[2 * i] = lo.f; off[2 * i + 1] = hi.f;
    }
    const float* rp = refp + (size_t)tok * 8 + l * 2;
    const int S = 128 >> l;
    const float Sf = (float)S;
    const float rx = rp[0] * Sf - 0.5f;
    const float ry = rp[1] * Sf - 0.5f;
#pragma unroll
    for (int p = 0; p < 4; p++) {
      const int idx = l * 4 + p;
      const float x = rx + off[p * 2 + 0];
      const float y = ry + off[p * 2 + 1];
      const float aw = w[idx] * inv;
      const float x0f = floorf(x), y0f = floorf(y);
      const int x0 = (int)x0f, y0 = (int)y0f;
      const float fx = x - x0f, fy = y - y0f;
      const bool xin0 = (x0 >= 0) & (x0 < S), xin1 = (x0 + 1 >= 0) & (x0 + 1 < S);
      const bool yin0 = (y0 >= 0) & (y0 < S), yin1 = (y0 + 1 >= 0) & (y0 + 1 < S);
      const int xc0 = min(max(x0, 0), S - 1), xc1 = min(max(x0 + 1, 0), S - 1);
      const int yc0 = min(max(y0, 0), S - 1), yc1 = min(max(y0 + 1, 0), S - 1);
      sW[g][h][idx] = make_float4(aw * (1.f - fx) * (1.f - fy) * (float)(xin0 & yin0),
                                  aw * fx * (1.f - fy)         * (float)(xin1 & yin0),
                                  aw * (1.f - fx) * fy         * (float)(xin0 & yin1),
                                  aw * fx * fy                 * (float)(xin1 & yin1));
      const int base = (yc0 * S + xc0) << 9;
      const int dx = (xc1 - xc0) << 9;            // 0 or 512
      const int dy = ((yc1 - yc0) * S) << 9;      // 0 or S*512 (low 9 bits zero)
      sI[g][h][idx] = make_int2(base, dy | (dx >> 9));
    }
  }
  __syncthreads();

  // ---- phase 2: thread = (g, h, dc); 16B loads, byte-offset addressing
  const int g = t >> 5, h = (t >> 2) & 7, dc = t & 3;
  const int tok = tok0 + g;
  const int b = tok / LQN;
  float acc[8] = {0.f, 0.f, 0.f, 0.f, 0.f, 0.f, 0.f, 0.f};
  const int ST[4] = {0, 16384, 20480, 21504};
#pragma unroll
  for (int l = 0; l < 4; l++) {
    const char* vbc = (const char*)(valb + ((size_t)(b * LQN + ST[l])) * 256 + h * 32 + dc * 8);
#pragma unroll
    for (int p = 0; p < 4; p++) {
      float4 W4 = sW[g][h][l * 4 + p];
      int2   I2 = sI[g][h][l * 4 + p];
      const int dx = (I2.y & 1) << 9;
      const int dy = I2.y & ~1;
      uint4 v00 = *(const uint4*)(vbc + I2.x);
      uint4 v10 = *(const uint4*)(vbc + I2.x + dx);
      uint4 v01 = *(const uint4*)(vbc + I2.x + dy);
      uint4 v11 = *(const uint4*)(vbc + I2.x + dy + dx);
      fma8(v00, W4.x, acc);
      fma8(v10, W4.y, acc);
      fma8(v01, W4.z, acc);
      fma8(v11, W4.w, acc);
    }
  }
  unsigned o[4];
#pragma unroll
  for (int i = 0; i < 4; i++)
    o[i] = (unsigned)f2bf(acc[2 * i]) | ((unsigned)f2bf(acc[2 * i + 1]) << 16);
  *(uint4*)(outb + (size_t)tok * 256 + h * 32 + dc * 8) = make_uint4(o[0], o[1], o[2], o[3]);
}

// ---- layernorm on bf16 pre-LN input; one wave per token (64 lanes x 4 elems)
template <int OUT_F32>
__global__ __launch_bounds__(256) void ln_kernel(const ushort4* __restrict__ in,
                                                 const float* __restrict__ g,
                                                 const float* __restrict__ beta,
                                                 void* __restrict__ outp) {
  const int wv = blockIdx.x * 4 + (threadIdx.x >> 6);
  const int lane = threadIdx.x & 63;
  const size_t idx = (size_t)wv * 64 + lane;
  ushort4 u = in[idx];
  float x0 = bf2f(u.x), x1 = bf2f(u.y), x2 = bf2f(u.z), x3 = bf2f(u.w);
  float sum = x0 + x1 + x2 + x3;
#pragma unroll
  for (int o = 32; o >= 1; o >>= 1) sum += __shfl_xor(sum, o, 64);
  const float mu = sum * (1.f / 256.f);
  float d0 = x0 - mu, d1 = x1 - mu, d2 = x2 - mu, d3 = x3 - mu;
  float ss = d0 * d0 + d1 * d1 + d2 * d2 + d3 * d3;
#pragma unroll
  for (int o = 32; o >= 1; o >>= 1) ss += __shfl_xor(ss, o, 64);
  const float rs = rsqrtf(ss * (1.f / 256.f) + 1e-5f);
  float4 gg = ((const float4*)g)[lane], bb = ((const float4*)beta)[lane];
  float y0 = d0 * rs * gg.x + bb.x;
  float y1 = d1 * rs * gg.y + bb.y;
  float y2 = d2 * rs * gg.z + bb.z;
  float y3 = d3 * rs * gg.w + bb.w;
  if (OUT_F32) ((float4*)outp)[idx] = make_float4(y0, y1, y2, y3);
  else ((ushort4*)outp)[idx] = make_ushort4(f2bf(y0), f2bf(y1), f2bf(y2), f2bf(y3));
}

extern "C" void kernel_launch(void* const* d_in, const int* in_sizes, int n_in,
                              void* d_out, int out_size, void* d_ws, size_t ws_size,
                              hipStream_t stream) {
  (void)in_sizes; (void)n_in; (void)out_size; (void)ws_size;
  const float* src    = (const float*)d_in[0];
  const float* pos    = (const float*)d_in[1];
  const float* refp   = (const float*)d_in[2];
  const float* W_off  = (const float*)d_in[3];
  const float* b_off  = (const float*)d_in[4];
  const float* W_attn = (const float*)d_in[5];
  const float* b_attn = (const float*)d_in[6];
  const float* W_val  = (const float*)d_in[7];
  const float* b_val  = (const float*)d_in[8];
  const float* W_out  = (const float*)d_in[9];
  const float* b_out  = (const float*)d_in[10];
  const float* ln1_g  = (const float*)d_in[11];
  const float* ln1_b  = (const float*)d_in[12];
  const float* W1     = (const float*)d_in[13];
  const float* b1     = (const float*)d_in[14];
  const float* W2     = (const float*)d_in[15];
  const float* b2     = (const float*)d_in[16];
  const float* ln2_g  = (const float*)d_in[17];
  const float* ln2_b  = (const float*)d_in[18];

  char* ws = (char*)d_ws;
  unsigned short* Wt_val = (unsigned short*)ws;          // 65536
  unsigned short* Wt_oa  = Wt_val + 65536;               // 98304
  unsigned short* Wt_out = Wt_oa + 98304;                // 65536
  unsigned short* Wt_1   = Wt_out + 65536;               // 262144
  unsigned short* Wt_2   = Wt_1 + 262144;                // 262144
  float*          b_oa   = (float*)(Wt_2 + 262144);      // 384
  const size_t WPOOL = 2u * 1024 * 1024;

  const size_t SZ_bf = (size_t)TOKS * 256 * 2;           // 22.3 MB
  const size_t SZ_oa = (size_t)TOKS * 384 * 2;           // 33.4 MB

  unsigned short* srcb = (unsigned short*)(ws + WPOOL);
  unsigned short* qb   = (unsigned short*)(ws + WPOOL + SZ_bf);
  unsigned short* valb = (unsigned short*)(ws + WPOOL + 2 * SZ_bf);
  unsigned short* oab  = (unsigned short*)(ws + WPOOL + 3 * SZ_bf);
  unsigned short* h_bf = (unsigned short*)(ws + WPOOL + 3 * SZ_bf + SZ_oa);
  unsigned short* hb   = (unsigned short*)(ws + WPOOL + 3 * SZ_bf + SZ_oa + SZ_bf);
  // aliases (lifetime-disjoint):
  unsigned short* attnoutb = qb;     // deform out; qb dead after proj
  unsigned short* preLN1b  = valb;   // out-gemm out; valb dead after deform
  unsigned short* preLN2b  = valb;   // W2 out; preLN1b dead after LN1

  // 1. prep + weight transposes + bias concat (one launch)
  prewt_kernel<<<13826, 256, 0, stream>>>(src, pos, srcb, qb,
                                          W_val, W_off, W_attn, W_out, W1, W2, b_off, b_attn,
                                          Wt_val, Wt_oa, Wt_out, Wt_1, Wt_2, b_oa);

  // 2. merged projections: value (N=256) + off/attn (N=384)
  proj_kernel<<<dim3(340, 5), 256, 0, stream>>>(srcb, qb, Wt_val, Wt_oa, b_val, b_oa,
                                                valb, oab);

  // 3. deformable attention (8 tokens/block, XCD-swizzled)
  deform_kernel<<<TOKS / 8, 256, 0, stream>>>(valb, oab, refp, attnoutb);

  // 4. out-proj + residual(src) -> preLN1 (bf16); LN1 -> h_bf
  gemm_out_kernel<<<dim3(340, 2), 256, 0, stream>>>(attnoutb, Wt_out, b_out, srcb, preLN1b);
  ln_kernel<0><<<10880, 256, 0, stream>>>((const ushort4*)preLN1b, ln1_g, ln1_b, h_bf);

  // 5. FFN: W1+relu -> hb; W2 + residual(h) -> preLN2 (bf16)
  gemm_ffn1_kernel<<<dim3(340, 8), 256, 0, stream>>>(h_bf, Wt_1, b1, hb);
  gemm_ffn2_kernel<<<dim3(340, 2), 256, 0, stream>>>(hb, Wt_2, b2, h_bf, preLN2b);

  // 6. LN2 -> d_out (f32)
  ln_kernel<1><<<10880, 256, 0, stream>>>((const ushort4*)preLN2b, ln2_g, ln2_b, d_out);
}

// Round 2
// 436.978 us; speedup vs baseline: 1.0479x; 1.0479x over previous
//
#include <hip/hip_runtime.h>

typedef __bf16 bf16x8 __attribute__((ext_vector_type(8)));
typedef float f32x4 __attribute__((ext_vector_type(4)));

static constexpr int TOKS = 43520;   // B * LQ
static constexpr int LQN  = 21760;

__device__ __forceinline__ unsigned short f2bf(float f) {
  union { float f; unsigned u; } v; v.f = f;
  return (unsigned short)((v.u + 0x7fffu + ((v.u >> 16) & 1u)) >> 16);
}
__device__ __forceinline__ float bf2f(unsigned short b) {
  union { unsigned u; float f; } v; v.u = ((unsigned)b) << 16; return v.f;
}

// ---- fused prep + weight transpose + bias concat (one launch)
__global__ __launch_bounds__(256) void prewt_kernel(
    const float* __restrict__ src, const float* __restrict__ pos,
    unsigned short* __restrict__ srcb, unsigned short* __restrict__ qb,
    const float* __restrict__ W_val, const float* __restrict__ W_off,
    const float* __restrict__ W_attn, const float* __restrict__ W_out,
    const float* __restrict__ W1, const float* __restrict__ W2,
    const float* __restrict__ b_off, const float* __restrict__ b_attn,
    unsigned short* __restrict__ Wt_val, unsigned short* __restrict__ Wt_oa,
    unsigned short* __restrict__ Wt_out,
    unsigned short* __restrict__ Wt_1, unsigned short* __restrict__ Wt_2,
    float* __restrict__ b_oa) {
  const int bid = blockIdx.x;
  if (bid < 10880) {
    int i = bid * 256 + threadIdx.x;
    float4 s = ((const float4*)src)[i], p = ((const float4*)pos)[i];
    ((ushort4*)srcb)[i] = make_ushort4(f2bf(s.x), f2bf(s.y), f2bf(s.z), f2bf(s.w));
    ((ushort4*)qb)[i]   = make_ushort4(f2bf(s.x + p.x), f2bf(s.y + p.y),
                                       f2bf(s.z + p.z), f2bf(s.w + p.w));
    return;
  }
  int gid = (bid - 10880) * 256 + threadIdx.x;
  if (gid >= 754048) return;
  if (gid >= 753664) {
    int i = gid - 753664;
    b_oa[i] = (i < 256) ? b_off[i] : b_attn[i - 256];
    return;
  }
  const float* W; unsigned short* Wt; int idx, K, nsh;
  if (gid < 65536)       { W = W_val;  Wt = Wt_val;          idx = gid;          K = 256;  nsh = 8;  }
  else if (gid < 131072) { W = W_off;  Wt = Wt_oa;           idx = gid - 65536;  K = 256;  nsh = 8;  }
  else if (gid < 163840) { W = W_attn; Wt = Wt_oa + 65536;   idx = gid - 131072; K = 256;  nsh = 7;  }
  else if (gid < 229376) { W = W_out;  Wt = Wt_out;          idx = gid - 163840; K = 256;  nsh = 8;  }
  else if (gid < 491520) { W = W1;     Wt = Wt_1;            idx = gid - 229376; K = 256;  nsh = 10; }
  else                   { W = W2;     Wt = Wt_2;            idx = gid - 491520; K = 1024; nsh = 8;  }
  int k = idx >> nsh, n = idx & ((1 << nsh) - 1);
  Wt[n * K + k] = f2bf(W[idx]);
}

// ---- R0 GEMM body (proven): padded LDS, reg staging, ONE barrier per K-iter.
// Used only by proj (N=640, awkward for BN=256 tiles). OUTOP: 1=bf16
template <int K, int OUTOP>
__device__ __forceinline__ void gemm_body(unsigned short* __restrict__ As,
                                          unsigned short* __restrict__ Bs,
                                          const unsigned short* __restrict__ A,
                                          const unsigned short* __restrict__ Bt,
                                          const float* __restrict__ bias,
                                          const unsigned short* __restrict__ res,
                                          unsigned short* __restrict__ Cp,
                                          int N, int bm, int bn) {
  const int t = threadIdx.x;
  const int wave = t >> 6, lane = t & 63;
  const int wm = (wave & 1) << 6, wn = (wave >> 1) << 6;
  const int lr = lane & 15, lq = lane >> 4;
  const int row0 = t >> 2, cb0 = (t & 3) << 3;
  f32x4 acc[4][4] = {};
  const unsigned short* ga = A  + (size_t)(bm * 128 + row0) * K + cb0;
  const unsigned short* gb = Bt + (size_t)(bn * 128 + row0) * K + cb0;
  const size_t gs = (size_t)64 * K;
  uint4 pa0 = *(const uint4*)ga;
  uint4 pa1 = *(const uint4*)(ga + gs);
  uint4 pb0 = *(const uint4*)gb;
  uint4 pb1 = *(const uint4*)(gb + gs);
  int p = 0;
#pragma unroll 1
  for (int k0 = 0; k0 < K; k0 += 32) {
    unsigned short* Ab = As + p * 5120;
    unsigned short* Bb = Bs + p * 5120;
    *(uint4*)&Ab[row0 * 40 + cb0] = pa0;
    *(uint4*)&Ab[(row0 + 64) * 40 + cb0] = pa1;
    *(uint4*)&Bb[row0 * 40 + cb0] = pb0;
    *(uint4*)&Bb[(row0 + 64) * 40 + cb0] = pb1;
    __syncthreads();
    if (k0 + 32 < K) {
      pa0 = *(const uint4*)(ga + k0 + 32);
      pa1 = *(const uint4*)(ga + gs + k0 + 32);
      pb0 = *(const uint4*)(gb + k0 + 32);
      pb1 = *(const uint4*)(gb + gs + k0 + 32);
    }
    bf16x8 af[4], bfr[4];
#pragma unroll
    for (int i = 0; i < 4; i++) af[i] = *(const bf16x8*)&Ab[(wm + i * 16 + lr) * 40 + lq * 8];
#pragma unroll
    for (int j = 0; j < 4; j++) bfr[j] = *(const bf16x8*)&Bb[(wn + j * 16 + lr) * 40 + lq * 8];
#pragma unroll
    for (int i = 0; i < 4; i++)
#pragma unroll
      for (int j = 0; j < 4; j++)
        acc[i][j] = __builtin_amdgcn_mfma_f32_16x16x32_bf16(af[i], bfr[j], acc[i][j], 0, 0, 0);
    p ^= 1;
  }
  const int rb = bm * 128 + wm + lq * 4;
  const int cbase = bn * 128 + wn + lr;
#pragma unroll
  for (int j = 0; j < 4; j++) {
    const int col = cbase + j * 16;
    const float bv = bias[col];
#pragma unroll
    for (int i = 0; i < 4; i++) {
#pragma unroll
      for (int r = 0; r < 4; r++) {
        float v = acc[i][j][r] + bv;
        size_t o = (size_t)(rb + i * 16 + r) * N + col;
        if (OUTOP == 1) Cp[o] = f2bf(v);
        else if (OUTOP == 2) Cp[o] = f2bf(fmaxf(v, 0.f));
        else Cp[o] = f2bf(v + bf2f(res[o]));
      }
    }
  }
}

__global__ __launch_bounds__(256) void proj_kernel(
    const unsigned short* __restrict__ srcb, const unsigned short* __restrict__ qb,
    const unsigned short* __restrict__ Wt_val, const unsigned short* __restrict__ Wt_oa,
    const float* __restrict__ b_val, const float* __restrict__ b_oa,
    unsigned short* __restrict__ valb, unsigned short* __restrict__ oab) {
  __shared__ unsigned short As[2 * 5120];
  __shared__ unsigned short Bs[2 * 5120];
  const int bn = blockIdx.y;
  if (bn < 2)
    gemm_body<256, 1>(As, Bs, srcb, Wt_val, b_val, nullptr, valb, 256, blockIdx.x, bn);
  else
    gemm_body<256, 1>(As, Bs, qb, Wt_oa, b_oa, nullptr, oab, 384, blockIdx.x, bn - 2);
}

// ---- BN=256 GEMM body with optional fused LayerNorm epilogue.
// Block = 128 rows x 256 cols, 4 waves as 2m x 2n (wave tile 64x128), acc[4][8].
// MODE 0: relu -> bf16 (ffn1).  MODE 1: +res, LN -> bf16 (out-proj+LN1).
// MODE 2: +res, LN -> f32 (ffn2+LN2).
template <int K, int MODE>
__device__ __forceinline__ void big_body(unsigned short* __restrict__ As,
                                         unsigned short* __restrict__ Bs,
                                         const unsigned short* __restrict__ A,
                                         const unsigned short* __restrict__ Bt,
                                         const float* __restrict__ bias,
                                         const unsigned short* __restrict__ res,
                                         const float* __restrict__ gamma,
                                         const float* __restrict__ beta,
                                         void* __restrict__ outp,
                                         int N, int bm, int bn) {
  const int t = threadIdx.x;
  const int wave = t >> 6, lane = t & 63;
  const int wm = (wave & 1) << 6, wn = (wave >> 1) << 7;   // wn in {0,128}
  const int lr = lane & 15, lq = lane >> 4;
  const int row0 = t >> 2, cb0 = (t & 3) << 3;
  f32x4 acc[4][8] = {};
  const unsigned short* ga = A  + (size_t)(bm * 128 + row0) * K + cb0;
  const unsigned short* gb = Bt + (size_t)(bn * 256 + row0) * K + cb0;
  const size_t gs = (size_t)64 * K;
  uint4 pa0 = *(const uint4*)ga;
  uint4 pa1 = *(const uint4*)(ga + gs);
  uint4 pb0 = *(const uint4*)gb;
  uint4 pb1 = *(const uint4*)(gb + gs);
  uint4 pb2 = *(const uint4*)(gb + 2 * gs);
  uint4 pb3 = *(const uint4*)(gb + 3 * gs);
  int p = 0;
#pragma unroll 1
  for (int k0 = 0; k0 < K; k0 += 32) {
    unsigned short* Ab = As + p * 5120;
    unsigned short* Bb = Bs + p * 10240;
    *(uint4*)&Ab[row0 * 40 + cb0] = pa0;
    *(uint4*)&Ab[(row0 + 64) * 40 + cb0] = pa1;
    *(uint4*)&Bb[row0 * 40 + cb0] = pb0;
    *(uint4*)&Bb[(row0 + 64) * 40 + cb0] = pb1;
    *(uint4*)&Bb[(row0 + 128) * 40 + cb0] = pb2;
    *(uint4*)&Bb[(row0 + 192) * 40 + cb0] = pb3;
    __syncthreads();
    if (k0 + 32 < K) {
      pa0 = *(const uint4*)(ga + k0 + 32);
      pa1 = *(const uint4*)(ga + gs + k0 + 32);
      pb0 = *(const uint4*)(gb + k0 + 32);
      pb1 = *(const uint4*)(gb + gs + k0 + 32);
      pb2 = *(const uint4*)(gb + 2 * gs + k0 + 32);
      pb3 = *(const uint4*)(gb + 3 * gs + k0 + 32);
    }
    bf16x8 af[4], bfr[8];
#pragma unroll
    for (int i = 0; i < 4; i++) af[i]  = *(const bf16x8*)&Ab[(wm + i * 16 + lr) * 40 + lq * 8];
#pragma unroll
    for (int j = 0; j < 8; j++) bfr[j] = *(const bf16x8*)&Bb[(wn + j * 16 + lr) * 40 + lq * 8];
#pragma unroll
    for (int i = 0; i < 4; i++)
#pragma unroll
      for (int j = 0; j < 8; j++)
        acc[i][j] = __builtin_amdgcn_mfma_f32_16x16x32_bf16(af[i], bfr[j], acc[i][j], 0, 0, 0);
    p ^= 1;
  }
  // C/D map: col = lane&15, row = (lane>>4)*4 + reg
  const int rb = bm * 128 + wm + lq * 4;
  if (MODE == 0) {
    const int cbase = bn * 256 + wn + lr;
#pragma unroll
    for (int j = 0; j < 8; j++) {
      const int col = cbase + j * 16;
      const float bv = bias[col];
#pragma unroll
      for (int i = 0; i < 4; i++)
#pragma unroll
        for (int r = 0; r < 4; r++) {
          float v = acc[i][j][r] + bv;
          ((unsigned short*)outp)[(size_t)(rb + i * 16 + r) * N + col] = f2bf(fmaxf(v, 0.f));
        }
    }
    return;
  }
  // ---- fused LayerNorm epilogue (N == 256, bn == 0)
  __syncthreads();                       // LDS about to be reused for reduction
  float* red = (float*)As;               // [sum|sq][wnIdx][128 rows] = 512 floats
  const int wnIdx = wave >> 1;
  float vsum[4][4], vsq[4][4];
#pragma unroll
  for (int i = 0; i < 4; i++)
#pragma unroll
    for (int r = 0; r < 4; r++) { vsum[i][r] = 0.f; vsq[i][r] = 0.f; }
#pragma unroll
  for (int j = 0; j < 8; j++) {
    const int col = wn + j * 16 + lr;
    const float bv = bias[col];
#pragma unroll
    for (int i = 0; i < 4; i++)
#pragma unroll
      for (int r = 0; r < 4; r++) {
        const int grow = rb + i * 16 + r;
        float v = acc[i][j][r] + bv + bf2f(res[(size_t)grow * 256 + col]);
        acc[i][j][r] = v;
        vsum[i][r] += v;
        vsq[i][r]  += v * v;
      }
  }
#pragma unroll
  for (int m = 1; m <= 8; m <<= 1)
#pragma unroll
    for (int i = 0; i < 4; i++)
#pragma unroll
      for (int r = 0; r < 4; r++) {
        vsum[i][r] += __shfl_xor(vsum[i][r], m, 64);
        vsq[i][r]  += __shfl_xor(vsq[i][r],  m, 64);
      }
  if (lr == 0) {
#pragma unroll
    for (int i = 0; i < 4; i++)
#pragma unroll
      for (int r = 0; r < 4; r++) {
        const int lrow = wm + i * 16 + lq * 4 + r;
        red[wnIdx * 128 + lrow]       = vsum[i][r];
        red[256 + wnIdx * 128 + lrow] = vsq[i][r];
      }
  }
  __syncthreads();
  float mu[4][4], rstd[4][4];
#pragma unroll
  for (int i = 0; i < 4; i++)
#pragma unroll
    for (int r = 0; r < 4; r++) {
      const int lrow = wm + i * 16 + lq * 4 + r;
      const float ts = vsum[i][r] + red[(1 - wnIdx) * 128 + lrow];
      const float tq = vsq[i][r]  + red[256 + (1 - wnIdx) * 128 + lrow];
      const float m_ = ts * (1.f / 256.f);
      float var = tq * (1.f / 256.f) - m_ * m_;
      mu[i][r] = m_;
      rstd[i][r] = rsqrtf(var + 1e-5f);
    }
#pragma unroll
  for (int j = 0; j < 8; j++) {
    const int col = wn + j * 16 + lr;
    const float gg = gamma[col], bb = beta[col];
#pragma unroll
    for (int i = 0; i < 4; i++)
#pragma unroll
      for (int r = 0; r < 4; r++) {
        const int grow = rb + i * 16 + r;
        const float y = (acc[i][j][r] - mu[i][r]) * rstd[i][r] * gg + bb;
        if (MODE == 1) ((unsigned short*)outp)[(size_t)grow * 256 + col] = f2bf(y);
        else           ((float*)outp)[(size_t)grow * 256 + col] = y;
      }
  }
}

__global__ __launch_bounds__(256, 2) void out_ln_kernel(
    const unsigned short* __restrict__ A, const unsigned short* __restrict__ Bt,
    const float* __restrict__ bias, const unsigned short* __restrict__ res,
    const float* __restrict__ gamma, const float* __restrict__ beta,
    unsigned short* __restrict__ C) {
  __shared__ unsigned short As[2 * 5120];
  __shared__ unsigned short Bs[2 * 10240];
  big_body<256, 1>(As, Bs, A, Bt, bias, res, gamma, beta, C, 256, blockIdx.x, 0);
}

__global__ __launch_bounds__(256, 2) void ffn1_kernel(
    const unsigned short* __restrict__ A, const unsigned short* __restrict__ Bt,
    const float* __restrict__ bias, unsigned short* __restrict__ C) {
  __shared__ unsigned short As[2 * 5120];
  __shared__ unsigned short Bs[2 * 10240];
  big_body<256, 0>(As, Bs, A, Bt, bias, nullptr, nullptr, nullptr, C, 1024,
                   blockIdx.x, blockIdx.y);
}

__global__ __launch_bounds__(256, 2) void ffn2_ln_kernel(
    const unsigned short* __restrict__ A, const unsigned short* __restrict__ Bt,
    const float* __restrict__ bias, const unsigned short* __restrict__ res,
    const float* __restrict__ gamma, const float* __restrict__ beta,
    float* __restrict__ C) {
  __shared__ unsigned short As[2 * 5120];
  __shared__ unsigned short Bs[2 * 10240];
  big_body<1024, 2>(As, Bs, A, Bt, bias, res, gamma, beta, C, 256, blockIdx.x, 0);
}

// ---- bf16x8 (uint4) fused unpack+FMA into fp32 acc
__device__ __forceinline__ void fma8(uint4 v, float w, float* a) {
  const unsigned uu[4] = {v.x, v.y, v.z, v.w};
#pragma unroll
  for (int i = 0; i < 4; i++) {
    union { unsigned u; float f; } lo, hi;
    lo.u = uu[i] << 16;
    hi.u = uu[i] & 0xffff0000u;
    a[2 * i]     += w * lo.f;
    a[2 * i + 1] += w * hi.f;
  }
}

// ---- deformable attention (R0 exact): two-phase, int4 byte-offset tables
__global__ __launch_bounds__(256) void deform_kernel(const unsigned short* __restrict__ valb,
                                                     const unsigned short* __restrict__ oab,
                                                     const float* __restrict__ refp,
                                                     unsigned short* __restrict__ outb) {
  __shared__ float4 sW[8][8][17];   // 4 corner weights (x attn)
  __shared__ int4   sI[8][8][17];   // 4 corner BYTE offsets (idx*512)
  const int t = threadIdx.x;
  const int bid = blockIdx.x;                     // 5440 blocks
  const int nb = (bid & 7) * 680 + (bid >> 3);    // XCD-contiguous slices
  const int tok0 = nb * 8;

  {
    const int g = t >> 5, h = (t >> 2) & 7, l = t & 3;
    const int tok = tok0 + g;
    const unsigned short* lg = oab + (size_t)tok * 384 + 256 + h * 16;
    uint4 lv0 = ((const uint4*)lg)[0];
    uint4 lv1 = ((const uint4*)lg)[1];
    const unsigned lw[8] = {lv0.x, lv0.y, lv0.z, lv0.w, lv1.x, lv1.y, lv1.z, lv1.w};
    float w[16];
#pragma unroll
    for (int i = 0; i < 8; i++) {
      union { unsigned u; float f; } lo, hi;
      lo.u = lw[i] << 16; hi.u = lw[i] & 0xffff0000u;
      w[2 * i] = lo.f; w[2 * i + 1] = hi.f;
    }
    float mx = -1e30f;
#pragma unroll
    for (int i = 0; i < 16; i++) mx = fmaxf(mx, w[i]);
    float s = 0.f;
#pragma unroll
    for (int i = 0; i < 16; i++) { w[i] = __expf(w[i] - mx); s += w[i]; }
    const float inv = 1.f / s;
    uint4 ov = *(const uint4*)(oab + (size_t)tok * 384 + h * 32 + l * 8);
    const unsigned owv[4] = {ov.x, ov.y, ov.z, ov.w};
    float off[8];
#pragma unroll
    for (int i = 0; i < 4; i++) {
      union { unsigned u; float f; } lo, hi;
      lo.u = owv[i] << 16; hi.u = owv[i] & 0xffff0000u;
      off[2 * i] = lo.f; off[2 * i + 1] = hi.f;
    }
    const float* rp = refp + (size_t)tok * 8 + l * 2;
    const int S = 128 >> l;
    const float Sf = (float)S;
    const float rx = rp[0] * Sf - 0.5f;
    const float ry = rp[1] * Sf - 0.5f;
#pragma unroll
    for (int p = 0; p < 4; p++) {
      const int idx = l * 4 + p;
      const float x = rx + off[p * 2 + 0];
      const float y = ry + off[p * 2 + 1];
      const float aw = w[idx] * inv;
      const float x0f = floorf(x), y0f = floorf(y);
      const int x0 = (int)x0f, y0 = (int)y0f;
      const float fx = x - x0f, fy = y - y0f;
      const bool xin0 = (x0 >= 0) & (x0 < S), xin1 = (x0 + 1 >= 0) & (x0 + 1 < S);
      const bool yin0 = (y0 >= 0) & (y0 < S), yin1 = (y0 + 1 >= 0) & (y0 + 1 < S);
      const int xc0 = min(max(x0, 0), S - 1), xc1 = min(max(x0 + 1, 0), S - 1);
      const int yc0 = min(max(y0, 0), S - 1), yc1 = min(max(y0 + 1, 0), S - 1);
      sW[g][h][idx] = make_float4(aw * (1.f - fx) * (1.f - fy) * (float)(xin0 & yin0),
                                  aw * fx * (1.f - fy)         * (float)(xin1 & yin0),
                                  aw * (1.f - fx) * fy         * (float)(xin0 & yin1),
                                  aw * fx * fy                 * (float)(xin1 & yin1));
      sI[g][h][idx] = make_int4((yc0 * S + xc0) << 9, (yc0 * S + xc1) << 9,
                                (yc1 * S + xc0) << 9, (yc1 * S + xc1) << 9);
    }
  }
  __syncthreads();

  const int g = t >> 5, h = (t >> 2) & 7, dc = t & 3;
  const int tok = tok0 + g;
  const int b = tok / LQN;
  float acc[8] = {0.f, 0.f, 0.f, 0.f, 0.f, 0.f, 0.f, 0.f};
  const int ST[4] = {0, 16384, 20480, 21504};
#pragma unroll
  for (int l = 0; l < 4; l++) {
    const char* vbc = (const char*)(valb + ((size_t)(b * LQN + ST[l])) * 256 + h * 32 + dc * 8);
#pragma unroll
    for (int p = 0; p < 4; p++) {
      float4 W4 = sW[g][h][l * 4 + p];
      int4   I4 = sI[g][h][l * 4 + p];
      uint4 v00 = *(const uint4*)(vbc + I4.x);
      uint4 v10 = *(const uint4*)(vbc + I4.y);
      uint4 v01 = *(const uint4*)(vbc + I4.z);
      uint4 v11 = *(const uint4*)(vbc + I4.w);
      fma8(v00, W4.x, acc);
      fma8(v10, W4.y, acc);
      fma8(v01, W4.z, acc);
      fma8(v11, W4.w, acc);
    }
  }
  unsigned o[4];
#pragma unroll
  for (int i = 0; i < 4; i++)
    o[i] = (unsigned)f2bf(acc[2 * i]) | ((unsigned)f2bf(acc[2 * i + 1]) << 16);
  *(uint4*)(outb + (size_t)tok * 256 + h * 32 + dc * 8) = make_uint4(o[0], o[1], o[2], o[3]);
}

extern "C" void kernel_launch(void* const* d_in, const int* in_sizes, int n_in,
                              void* d_out, int out_size, void* d_ws, size_t ws_size,
                              hipStream_t stream) {
  (void)in_sizes; (void)n_in; (void)out_size; (void)ws_size;
  const float* src    = (const float*)d_in[0];
  const float* pos    = (const float*)d_in[1];
  const float* refp   = (const float*)d_in[2];
  const float* W_off  = (const float*)d_in[3];
  const float* b_off  = (const float*)d_in[4];
  const float* W_attn = (const float*)d_in[5];
  const float* b_attn = (const float*)d_in[6];
  const float* W_val  = (const float*)d_in[7];
  const float* b_val  = (const float*)d_in[8];
  const float* W_out  = (const float*)d_in[9];
  const float* b_out  = (const float*)d_in[10];
  const float* ln1_g  = (const float*)d_in[11];
  const float* ln1_b  = (const float*)d_in[12];
  const float* W1     = (const float*)d_in[13];
  const float* b1     = (const float*)d_in[14];
  const float* W2     = (const float*)d_in[15];
  const float* b2     = (const float*)d_in[16];
  const float* ln2_g  = (const float*)d_in[17];
  const float* ln2_b  = (const float*)d_in[18];

  char* ws = (char*)d_ws;
  unsigned short* Wt_val = (unsigned short*)ws;          // 65536
  unsigned short* Wt_oa  = Wt_val + 65536;               // 98304
  unsigned short* Wt_out = Wt_oa + 98304;                // 65536
  unsigned short* Wt_1   = Wt_out + 65536;               // 262144
  unsigned short* Wt_2   = Wt_1 + 262144;                // 262144
  float*          b_oa   = (float*)(Wt_2 + 262144);      // 384
  const size_t WPOOL = 2u * 1024 * 1024;

  const size_t SZ_bf = (size_t)TOKS * 256 * 2;           // 22.3 MB
  const size_t SZ_oa = (size_t)TOKS * 384 * 2;           // 33.4 MB

  unsigned short* srcb = (unsigned short*)(ws + WPOOL);
  unsigned short* qb   = (unsigned short*)(ws + WPOOL + SZ_bf);
  unsigned short* valb = (unsigned short*)(ws + WPOOL + 2 * SZ_bf);
  unsigned short* oab  = (unsigned short*)(ws + WPOOL + 3 * SZ_bf);
  unsigned short* h_bf = (unsigned short*)(ws + WPOOL + 3 * SZ_bf + SZ_oa);
  unsigned short* hb   = (unsigned short*)(ws + WPOOL + 3 * SZ_bf + SZ_oa + SZ_bf);
  // alias (lifetime-disjoint):
  unsigned short* attnoutb = qb;     // deform out; qb dead after proj

  // 1. prep + weight transposes + bias concat
  prewt_kernel<<<13826, 256, 0, stream>>>(src, pos, srcb, qb,
                                          W_val, W_off, W_attn, W_out, W1, W2, b_off, b_attn,
                                          Wt_val, Wt_oa, Wt_out, Wt_1, Wt_2, b_oa);

  // 2. merged projections: value (N=256) + off/attn (N=384)
  proj_kernel<<<dim3(340, 5), 256, 0, stream>>>(srcb, qb, Wt_val, Wt_oa, b_val, b_oa,
                                                valb, oab);

  // 3. deformable attention (8 tokens/block, XCD-swizzled)
  deform_kernel<<<TOKS / 8, 256, 0, stream>>>(valb, oab, refp, attnoutb);

  // 4. out-proj + residual(src) + LN1 fused -> h_bf (bf16)
  out_ln_kernel<<<340, 256, 0, stream>>>(attnoutb, Wt_out, b_out, srcb, ln1_g, ln1_b, h_bf);

  // 5. FFN1: W1 + relu -> hb (BN=256 tiles)
  ffn1_kernel<<<dim3(340, 4), 256, 0, stream>>>(h_bf, Wt_1, b1, hb);

  // 6. FFN2 + residual(h) + LN2 fused -> d_out (f32)
  ffn2_ln_kernel<<<340, 256, 0, stream>>>(hb, Wt_2, b2, h_bf, ln2_g, ln2_b, (float*)d_out);
}